// Round 5
// baseline (277.697 us; speedup 1.0000x reference)
//
#include <hip/hip_runtime.h>
#include <hip/hip_bf16.h>
#include <math.h>

#define N_NODES 50000
#define N_EDGES 800000
#define HEADS 4
#define HID 32
#define D1 128
#define D2 64
#define NEG_SLOPE 0.2f
#define LN_EPS 1e-5f

#define NB_SCAN ((N_NODES + 255) / 256)  // 196
#define CAP 64
#define GB1 ((N_NODES + 127) / 128)      // 391 gemm blocks in fused K1
#define DEGB 784                          // degree blocks in K1 (grid-stride, ~4 edges/thread)

__device__ __forceinline__ float lrelu(float x) { return x > 0.f ? x : NEG_SLOPE * x; }
__device__ __forceinline__ float bf2f(__hip_bfloat16 v) { return __bfloat162float(v); }

// ---------------- K1: gemm1 (+att1 epilogue) fused with degree/rank ----------------
// Mapping: cg = tid>>5 (8 groups of 32). Wave wv covers cg {2wv,2wv+1} = head wv.
// Wlds reads are uniform per half-wave -> broadcast, no bank conflicts.
// LDS = 32 k-rows * 128 cols * 4B = 16 KB (K staged in 4 chunks).
__global__ __launch_bounds__(256) void gemm1_att1_degree_kernel(
    const float* __restrict__ X, const float* __restrict__ W,
    __hip_bfloat16* __restrict__ Y,
    const float* __restrict__ att_src, const float* __restrict__ att_dst,
    float* __restrict__ a_s, float* __restrict__ a_d,
    const int* __restrict__ dst, int* __restrict__ deg, int* __restrict__ rank) {
    __shared__ float Wlds[32 * 128];
    if (blockIdx.x >= GB1) {
        int t0 = (blockIdx.x - GB1) * 256 + threadIdx.x;
        const int stride = DEGB * 256;
#pragma unroll
        for (int u = 0; u < 4; ++u) {
            int i = t0 + u * stride;
            if (i < N_EDGES) rank[i] = atomicAdd(&deg[dst[i]], 1);
        }
        return;
    }
    int tid = threadIdx.x;
    int cg = tid >> 5;       // 0..7
    int rg = tid & 31;       // 0..31
    int c0 = cg * 16;
    int head = cg >> 1;
    int half = cg & 1;
    int r0 = blockIdx.x * 128 + rg * 4;

    float acc[4][16];
#pragma unroll
    for (int i = 0; i < 4; ++i)
#pragma unroll
        for (int j = 0; j < 16; ++j) acc[i][j] = 0.f;

    const float* xrow[4];
#pragma unroll
    for (int i = 0; i < 4; ++i) {
        int ri = r0 + i;
        if (ri >= N_NODES) ri = N_NODES - 1;
        xrow[i] = X + (size_t)ri * 128;
    }

    for (int kb = 0; kb < 128; kb += 32) {
        {   // stage 32 k-rows of W (contiguous 16 KB), coalesced
            const float4* s = (const float4*)(W + (size_t)kb * 128) + tid * 4;
            float4* d = (float4*)&Wlds[tid * 16];
            d[0] = s[0]; d[1] = s[1]; d[2] = s[2]; d[3] = s[3];
        }
        __syncthreads();
#pragma unroll
        for (int k = 0; k < 32; k += 4) {
            float4 xv[4];
#pragma unroll
            for (int i = 0; i < 4; ++i) xv[i] = *(const float4*)&xrow[i][kb + k];
#pragma unroll
            for (int kk = 0; kk < 4; ++kk) {
                const float* wrow = &Wlds[(k + kk) * 128 + c0];
                const float4 w0 = *(const float4*)(wrow + 0);
                const float4 w1 = *(const float4*)(wrow + 4);
                const float4 w2 = *(const float4*)(wrow + 8);
                const float4 w3 = *(const float4*)(wrow + 12);
#pragma unroll
                for (int i = 0; i < 4; ++i) {
                    float xk = (kk == 0) ? xv[i].x : (kk == 1) ? xv[i].y : (kk == 2) ? xv[i].z : xv[i].w;
                    acc[i][0]  += xk * w0.x; acc[i][1]  += xk * w0.y;
                    acc[i][2]  += xk * w0.z; acc[i][3]  += xk * w0.w;
                    acc[i][4]  += xk * w1.x; acc[i][5]  += xk * w1.y;
                    acc[i][6]  += xk * w1.z; acc[i][7]  += xk * w1.w;
                    acc[i][8]  += xk * w2.x; acc[i][9]  += xk * w2.y;
                    acc[i][10] += xk * w2.z; acc[i][11] += xk * w2.w;
                    acc[i][12] += xk * w3.x; acc[i][13] += xk * w3.y;
                    acc[i][14] += xk * w3.z; acc[i][15] += xk * w3.w;
                }
            }
        }
        __syncthreads();
    }

    // epilogue: att1 coeffs (pair-halves share a wave -> shfl_xor 32) + bf16 store
    float asv[16], adv[16];
#pragma unroll
    for (int j = 0; j < 16; ++j) {
        asv[j] = att_src[head * 32 + half * 16 + j];
        adv[j] = att_dst[head * 32 + half * 16 + j];
    }
#pragma unroll
    for (int i = 0; i < 4; ++i) {
        int r = r0 + i;
        float ps = 0.f, pd = 0.f;
#pragma unroll
        for (int j = 0; j < 16; ++j) {
            ps += acc[i][j] * asv[j];
            pd += acc[i][j] * adv[j];
        }
        ps += __shfl_xor(ps, 32, 64);
        pd += __shfl_xor(pd, 32, 64);
        if (r < N_NODES) {
            __hip_bfloat162* yp = (__hip_bfloat162*)(Y + (size_t)r * 128 + c0);
#pragma unroll
            for (int j = 0; j < 8; ++j) {
                __hip_bfloat162 p;
                p.x = __float2bfloat16(acc[i][2 * j]);
                p.y = __float2bfloat16(acc[i][2 * j + 1]);
                yp[j] = p;
            }
            if (half == 0) {
                a_s[r * 4 + head] = ps;
                a_d[r * 4 + head] = pd;
            }
        }
    }
}

// ---------------- scans ----------------
__global__ __launch_bounds__(256) void scan1_kernel(const int* __restrict__ deg,
                                                    int* __restrict__ rpl,
                                                    int* __restrict__ bsum) {
    int i = blockIdx.x * 256 + threadIdx.x;
    int v = (i < N_NODES) ? deg[i] : 0;
    int lane = threadIdx.x & 63;
    int w = threadIdx.x >> 6;
    int x = v;
#pragma unroll
    for (int off = 1; off < 64; off <<= 1) {
        int t = __shfl_up(x, off, 64);
        if (lane >= off) x += t;
    }
    __shared__ int wsum[4];
    if (lane == 63) wsum[w] = x;
    __syncthreads();
    int wo = 0;
    if (w > 0) wo += wsum[0];
    if (w > 1) wo += wsum[1];
    if (w > 2) wo += wsum[2];
    if (i <= N_NODES) rpl[i] = x - v + wo;
    if (threadIdx.x == 255) bsum[blockIdx.x] = x + wo;
}

__global__ __launch_bounds__(256) void scan2_kernel(const int* __restrict__ bsum,
                                                    int* __restrict__ boff) {
    int i = threadIdx.x;
    int v = (i < NB_SCAN) ? bsum[i] : 0;
    int lane = threadIdx.x & 63;
    int w = threadIdx.x >> 6;
    int x = v;
#pragma unroll
    for (int off = 1; off < 64; off <<= 1) {
        int t = __shfl_up(x, off, 64);
        if (lane >= off) x += t;
    }
    __shared__ int wsum[4];
    if (lane == 63) wsum[w] = x;
    __syncthreads();
    int wo = 0;
    if (w > 0) wo += wsum[0];
    if (w > 1) wo += wsum[1];
    if (w > 2) wo += wsum[2];
    if (i < NB_SCAN) boff[i] = x - v + wo;
}

// ---------------- scatter (no atomics: rank precomputed) ----------------
__global__ __launch_bounds__(256) void scatter_kernel(const int* __restrict__ src,
                                                      const int* __restrict__ dst,
                                                      const int* __restrict__ rpl,
                                                      const int* __restrict__ boff,
                                                      const int* __restrict__ rank,
                                                      int* __restrict__ col) {
    int i = blockIdx.x * blockDim.x + threadIdx.x;
    if (i < N_EDGES) {
        int d = dst[i];
        int pos = rpl[d] + boff[d >> 8] + rank[i];
        col[pos] = src[i];
    }
}

// ---------------- aggregation layer 1 ----------------
__global__ __launch_bounds__(256) void agg1_kernel(const __hip_bfloat16* __restrict__ h,
                                                   const float* __restrict__ a_s,
                                                   const float* __restrict__ a_d,
                                                   const int* __restrict__ rpl,
                                                   const int* __restrict__ boff,
                                                   const int* __restrict__ col,
                                                   const float* __restrict__ b1,
                                                   const float* __restrict__ gamma,
                                                   const float* __restrict__ beta,
                                                   float* __restrict__ out) {
    __shared__ int colsh[4][CAP];
    __shared__ float wsh[4][CAP * 4];
    int wv = threadIdx.x >> 6;
    int lane = threadIdx.x & 63;
    int n = blockIdx.x * 4 + wv;
    int nn = (n < N_NODES) ? n : N_NODES - 1;
    int head = lane >> 4;
    int c = 2 * lane;

    const float4 ad4 = *(const float4*)&a_d[nn * 4];
    int beg = rpl[nn] + boff[nn >> 8];
    int end = rpl[nn + 1] + boff[(nn + 1) >> 8];
    int deg = end - beg;

    float den0 = 0.f, den1 = 0.f, den2 = 0.f, den3 = 0.f;
    for (int t = lane; t < deg; t += 64) {
        int s = col[beg + t];
        const float4 as4 = *(const float4*)&a_s[s * 4];
        float w0 = __expf(lrelu(as4.x + ad4.x));
        float w1 = __expf(lrelu(as4.y + ad4.y));
        float w2 = __expf(lrelu(as4.z + ad4.z));
        float w3 = __expf(lrelu(as4.w + ad4.w));
        if (t < CAP) {
            colsh[wv][t] = s;
            *(float4*)&wsh[wv][t * 4] = make_float4(w0, w1, w2, w3);
        }
        den0 += w0; den1 += w1; den2 += w2; den3 += w3;
    }
#pragma unroll
    for (int m = 1; m < 64; m <<= 1) {
        den0 += __shfl_xor(den0, m, 64);
        den1 += __shfl_xor(den1, m, 64);
        den2 += __shfl_xor(den2, m, 64);
        den3 += __shfl_xor(den3, m, 64);
    }
    float adh = (head == 0) ? ad4.x : (head == 1) ? ad4.y : (head == 2) ? ad4.z : ad4.w;
    float wself = __expf(lrelu(a_s[nn * 4 + head] + adh));
    float den = ((head == 0) ? den0 : (head == 1) ? den1 : (head == 2) ? den2 : den3) + wself;

    __syncthreads();

    float ax0 = 0.f, ay0 = 0.f, ax1 = 0.f, ay1 = 0.f;
    int m0 = (deg < CAP) ? deg : CAP;
    int j = 0;
    for (; j + 3 < m0; j += 4) {
        int s0 = colsh[wv][j + 0], s1 = colsh[wv][j + 1];
        int s2 = colsh[wv][j + 2], s3 = colsh[wv][j + 3];
        float w0 = wsh[wv][(j + 0) * 4 + head], w1 = wsh[wv][(j + 1) * 4 + head];
        float w2 = wsh[wv][(j + 2) * 4 + head], w3 = wsh[wv][(j + 3) * 4 + head];
        __hip_bfloat162 h0 = ((const __hip_bfloat162*)h)[(size_t)s0 * 64 + lane];
        __hip_bfloat162 h1 = ((const __hip_bfloat162*)h)[(size_t)s1 * 64 + lane];
        __hip_bfloat162 h2v = ((const __hip_bfloat162*)h)[(size_t)s2 * 64 + lane];
        __hip_bfloat162 h3 = ((const __hip_bfloat162*)h)[(size_t)s3 * 64 + lane];
        ax0 += w0 * bf2f(h0.x); ay0 += w0 * bf2f(h0.y);
        ax1 += w1 * bf2f(h1.x); ay1 += w1 * bf2f(h1.y);
        ax0 += w2 * bf2f(h2v.x); ay0 += w2 * bf2f(h2v.y);
        ax1 += w3 * bf2f(h3.x); ay1 += w3 * bf2f(h3.y);
    }
    for (; j < m0; ++j) {
        int s = colsh[wv][j];
        float w = wsh[wv][j * 4 + head];
        __hip_bfloat162 hv = ((const __hip_bfloat162*)h)[(size_t)s * 64 + lane];
        ax0 += w * bf2f(hv.x); ay0 += w * bf2f(hv.y);
    }
    for (; j < deg; ++j) {
        int s = col[beg + j];
        float w = __expf(lrelu(a_s[s * 4 + head] + adh));
        __hip_bfloat162 hv = ((const __hip_bfloat162*)h)[(size_t)s * 64 + lane];
        ax0 += w * bf2f(hv.x); ay0 += w * bf2f(hv.y);
    }
    {
        __hip_bfloat162 hv = ((const __hip_bfloat162*)h)[(size_t)nn * 64 + lane];
        ax0 += wself * bf2f(hv.x); ay0 += wself * bf2f(hv.y);
    }
    float inv = 1.f / den;
    float vx = (ax0 + ax1) * inv + b1[c];
    float vy = (ay0 + ay1) * inv + b1[c + 1];

    float s1 = vx + vy, s2 = vx * vx + vy * vy;
#pragma unroll
    for (int m = 1; m < 64; m <<= 1) {
        s1 += __shfl_xor(s1, m, 64);
        s2 += __shfl_xor(s2, m, 64);
    }
    float mean = s1 * (1.f / 128.f);
    float var = s2 * (1.f / 128.f) - mean * mean;
    float r = rsqrtf(var + LN_EPS);
    float ox = fmaxf(0.f, (vx - mean) * r * gamma[c] + beta[c]);
    float oy = fmaxf(0.f, (vy - mean) * r * gamma[c + 1] + beta[c + 1]);
    if (n < N_NODES) *(float2*)&out[(size_t)n * 128 + c] = make_float2(ox, oy);
}

// ---------------- gemm2 + att2 epilogue ----------------
// cg = wave id (4 waves x 16 cols); W reads wave-uniform -> broadcast.
// LDS = 64 k-rows * 64 cols * 4B = 16 KB (K staged in 2 chunks); reused for att2 reduction.
__global__ __launch_bounds__(256) void gemm2_att2_kernel(const float* __restrict__ X,
                                                         const float* __restrict__ W,
                                                         __hip_bfloat16* __restrict__ Y,
                                                         const float* __restrict__ att_src,
                                                         const float* __restrict__ att_dst,
                                                         float* __restrict__ a_s,
                                                         float* __restrict__ a_d) {
    __shared__ float Wlds[64 * 64];
    int tid = threadIdx.x;
    int cg = tid >> 6;       // 0..3 (wave id)
    int rg = tid & 63;       // 0..63
    int c0 = cg * 16;
    int r0 = blockIdx.x * 128 + rg * 2;

    float acc[2][16];
#pragma unroll
    for (int i = 0; i < 2; ++i)
#pragma unroll
        for (int j = 0; j < 16; ++j) acc[i][j] = 0.f;

    const float* xrow[2];
#pragma unroll
    for (int i = 0; i < 2; ++i) {
        int ri = r0 + i;
        if (ri >= N_NODES) ri = N_NODES - 1;
        xrow[i] = X + (size_t)ri * 128;
    }

    for (int kb = 0; kb < 128; kb += 64) {
        {   // stage 64 k-rows of W2 (contiguous 16 KB)
            const float4* s = (const float4*)(W + (size_t)kb * 64) + tid * 4;
            float4* d = (float4*)&Wlds[tid * 16];
            d[0] = s[0]; d[1] = s[1]; d[2] = s[2]; d[3] = s[3];
        }
        __syncthreads();
#pragma unroll
        for (int k = 0; k < 64; k += 4) {
            float4 xv[2];
#pragma unroll
            for (int i = 0; i < 2; ++i) xv[i] = *(const float4*)&xrow[i][kb + k];
#pragma unroll
            for (int kk = 0; kk < 4; ++kk) {
                const float* wrow = &Wlds[(k + kk) * 64 + c0];
                const float4 w0 = *(const float4*)(wrow + 0);
                const float4 w1 = *(const float4*)(wrow + 4);
                const float4 w2 = *(const float4*)(wrow + 8);
                const float4 w3 = *(const float4*)(wrow + 12);
#pragma unroll
                for (int i = 0; i < 2; ++i) {
                    float xk = (kk == 0) ? xv[i].x : (kk == 1) ? xv[i].y : (kk == 2) ? xv[i].z : xv[i].w;
                    acc[i][0]  += xk * w0.x; acc[i][1]  += xk * w0.y;
                    acc[i][2]  += xk * w0.z; acc[i][3]  += xk * w0.w;
                    acc[i][4]  += xk * w1.x; acc[i][5]  += xk * w1.y;
                    acc[i][6]  += xk * w1.z; acc[i][7]  += xk * w1.w;
                    acc[i][8]  += xk * w2.x; acc[i][9]  += xk * w2.y;
                    acc[i][10] += xk * w2.z; acc[i][11] += xk * w2.w;
                    acc[i][12] += xk * w3.x; acc[i][13] += xk * w3.y;
                    acc[i][14] += xk * w3.z; acc[i][15] += xk * w3.w;
                }
            }
        }
        __syncthreads();
    }

    // Y store
#pragma unroll
    for (int i = 0; i < 2; ++i) {
        int r = r0 + i;
        if (r < N_NODES) {
            __hip_bfloat162* yp = (__hip_bfloat162*)(Y + (size_t)r * 64 + c0);
#pragma unroll
            for (int j = 0; j < 8; ++j) {
                __hip_bfloat162 p;
                p.x = __float2bfloat16(acc[i][2 * j]);
                p.y = __float2bfloat16(acc[i][2 * j + 1]);
                yp[j] = p;
            }
        }
    }

    // att2 coefficients: partial per (row, cg), cross-wave reduce via Wlds
    float ps[2], pd[2];
#pragma unroll
    for (int i = 0; i < 2; ++i) {
        ps[i] = 0.f; pd[i] = 0.f;
#pragma unroll
        for (int j = 0; j < 16; ++j) {
            ps[i] += acc[i][j] * att_src[c0 + j];
            pd[i] += acc[i][j] * att_dst[c0 + j];
        }
    }
    float* red = Wlds;  // safe: all threads passed final __syncthreads
#pragma unroll
    for (int i = 0; i < 2; ++i) {
        int rr = rg * 2 + i;
        red[rr * 4 + cg] = ps[i];
        red[512 + rr * 4 + cg] = pd[i];
    }
    __syncthreads();
    if (tid < 128) {
        int r = blockIdx.x * 128 + tid;
        float as = red[tid * 4 + 0] + red[tid * 4 + 1] + red[tid * 4 + 2] + red[tid * 4 + 3];
        float ad = red[512 + tid * 4 + 0] + red[512 + tid * 4 + 1] +
                   red[512 + tid * 4 + 2] + red[512 + tid * 4 + 3];
        if (r < N_NODES) {
            a_s[r] = as;
            a_d[r] = ad;
        }
    }
}

// ---------------- aggregation layer 2 ----------------
__global__ __launch_bounds__(256) void agg2_kernel(const __hip_bfloat16* __restrict__ h,
                                                   const float* __restrict__ a_s,
                                                   const float* __restrict__ a_d,
                                                   const int* __restrict__ rpl,
                                                   const int* __restrict__ boff,
                                                   const int* __restrict__ col,
                                                   const float* __restrict__ b2,
                                                   const float* __restrict__ gamma,
                                                   const float* __restrict__ beta,
                                                   float* __restrict__ out) {
    __shared__ int colsh[4][CAP];
    __shared__ float wsh[4][CAP];
    int wv = threadIdx.x >> 6;
    int lane = threadIdx.x & 63;
    int n = blockIdx.x * 4 + wv;
    int nn = (n < N_NODES) ? n : N_NODES - 1;

    float adh = a_d[nn];
    int beg = rpl[nn] + boff[nn >> 8];
    int end = rpl[nn + 1] + boff[(nn + 1) >> 8];
    int deg = end - beg;

    float den = 0.f;
    for (int t = lane; t < deg; t += 64) {
        int s = col[beg + t];
        float w = __expf(lrelu(a_s[s] + adh));
        if (t < CAP) {
            colsh[wv][t] = s;
            wsh[wv][t] = w;
        }
        den += w;
    }
#pragma unroll
    for (int m = 1; m < 64; m <<= 1) den += __shfl_xor(den, m, 64);
    float wself = __expf(lrelu(a_s[nn] + adh));
    den += wself;

    __syncthreads();

    float a0 = 0.f, a1 = 0.f;
    int m0 = (deg < CAP) ? deg : CAP;
    int j = 0;
    for (; j + 3 < m0; j += 4) {
        int s0 = colsh[wv][j + 0], s1 = colsh[wv][j + 1];
        int s2 = colsh[wv][j + 2], s3 = colsh[wv][j + 3];
        float w0 = wsh[wv][j + 0], w1 = wsh[wv][j + 1];
        float w2 = wsh[wv][j + 2], w3 = wsh[wv][j + 3];
        a0 += w0 * bf2f(h[(size_t)s0 * 64 + lane]);
        a1 += w1 * bf2f(h[(size_t)s1 * 64 + lane]);
        a0 += w2 * bf2f(h[(size_t)s2 * 64 + lane]);
        a1 += w3 * bf2f(h[(size_t)s3 * 64 + lane]);
    }
    for (; j < m0; ++j) {
        a0 += wsh[wv][j] * bf2f(h[(size_t)colsh[wv][j] * 64 + lane]);
    }
    for (; j < deg; ++j) {
        int s = col[beg + j];
        float w = __expf(lrelu(a_s[s] + adh));
        a0 += w * bf2f(h[(size_t)s * 64 + lane]);
    }
    a0 += wself * bf2f(h[(size_t)nn * 64 + lane]);

    float v = (a0 + a1) / den + b2[lane];

    float s1 = v, s2 = v * v;
#pragma unroll
    for (int m = 1; m < 64; m <<= 1) {
        s1 += __shfl_xor(s1, m, 64);
        s2 += __shfl_xor(s2, m, 64);
    }
    float mean = s1 * (1.f / 64.f);
    float var = s2 * (1.f / 64.f) - mean * mean;
    float r = rsqrtf(var + LN_EPS);
    if (n < N_NODES) out[(size_t)n * 64 + lane] = (v - mean) * r * gamma[lane] + beta[lane];
}

// ---------------- host ----------------
extern "C" void kernel_launch(void* const* d_in, const int* in_sizes, int n_in,
                              void* d_out, int out_size, void* d_ws, size_t ws_size,
                              hipStream_t stream) {
    const float* x        = (const float*)d_in[0];
    const int*   ei       = (const int*)d_in[1];
    const float* W1       = (const float*)d_in[2];
    const float* att_src1 = (const float*)d_in[3];
    const float* att_dst1 = (const float*)d_in[4];
    const float* b1       = (const float*)d_in[5];
    const float* gamma1   = (const float*)d_in[6];
    const float* beta1    = (const float*)d_in[7];
    const float* W2       = (const float*)d_in[8];
    const float* att_src2 = (const float*)d_in[9];
    const float* att_dst2 = (const float*)d_in[10];
    const float* b2       = (const float*)d_in[11];
    const float* gamma2   = (const float*)d_in[12];
    const float* beta2    = (const float*)d_in[13];
    const int* src = ei;
    const int* dst = ei + N_EDGES;
    float* out = (float*)d_out;

    char* ws = (char*)d_ws;
    size_t off = 0;
    auto alloc = [&](size_t bytes) -> void* {
        void* p = ws + off;
        off += bytes;
        off = (off + 255) & ~(size_t)255;
        return p;
    };
    __hip_bfloat16* h1pre = (__hip_bfloat16*)alloc((size_t)N_NODES * 128 * 2);
    __hip_bfloat16* h2pre = (__hip_bfloat16*)alloc((size_t)N_NODES * 64 * 2);
    float* a_s1   = (float*)alloc((size_t)N_NODES * 4 * 4);
    float* a_d1   = (float*)alloc((size_t)N_NODES * 4 * 4);
    float* h1n    = (float*)alloc((size_t)N_NODES * 128 * 4);
    float* a_s2   = (float*)alloc((size_t)N_NODES * 4);
    float* a_d2   = (float*)alloc((size_t)N_NODES * 4);
    int* deg      = (int*)alloc((size_t)N_NODES * 4);
    int* rpl      = (int*)alloc((size_t)(N_NODES + 1) * 4);
    int* col      = (int*)alloc((size_t)N_EDGES * 4);
    int* rank     = (int*)alloc((size_t)N_EDGES * 4);
    int* bsum     = (int*)alloc((size_t)NB_SCAN * 4);
    int* boff     = (int*)alloc((size_t)NB_SCAN * 4);

    hipMemsetAsync(deg, 0, (size_t)N_NODES * 4, stream);

    const int EB = (N_EDGES + 255) / 256;
    const int NWB = (N_NODES + 3) / 4;

    gemm1_att1_degree_kernel<<<GB1 + DEGB, 256, 0, stream>>>(
        x, W1, h1pre, att_src1, att_dst1, a_s1, a_d1, dst, deg, rank);
    scan1_kernel<<<NB_SCAN, 256, 0, stream>>>(deg, rpl, bsum);
    scan2_kernel<<<1, 256, 0, stream>>>(bsum, boff);
    scatter_kernel<<<EB, 256, 0, stream>>>(src, dst, rpl, boff, rank, col);

    agg1_kernel<<<NWB, 256, 0, stream>>>(h1pre, a_s1, a_d1, rpl, boff, col, b1, gamma1, beta1, h1n);

    gemm2_att2_kernel<<<(N_NODES + 127) / 128, 256, 0, stream>>>(
        h1n, W2, h2pre, att_src2, att_dst2, a_s2, a_d2);
    agg2_kernel<<<NWB, 256, 0, stream>>>(h2pre, a_s2, a_d2, rpl, boff, col, b2, gamma2, beta2, out);
}

// Round 6
// 261.948 us; speedup vs baseline: 1.0601x; 1.0601x over previous
//
#include <hip/hip_runtime.h>
#include <hip/hip_bf16.h>
#include <math.h>

#define N_NODES 50000
#define N_EDGES 800000
#define HEADS 4
#define HID 32
#define D1 128
#define D2 64
#define NEG_SLOPE 0.2f
#define LN_EPS 1e-5f

#define NB_SCAN ((N_NODES + 255) / 256)  // 196
#define CAP 64
#define GB1 (((N_NODES + 127) / 128) * 2)  // 782: 391 row-blocks x 2 col-halves
#define DEGB 784                            // degree blocks in K1 (grid-stride, ~4 edges/thread)

__device__ __forceinline__ float lrelu(float x) { return x > 0.f ? x : NEG_SLOPE * x; }
__device__ __forceinline__ float bf2f(__hip_bfloat16 v) { return __bfloat162float(v); }

// ---------------- K1: gemm1 (+att1 epilogue) fused with degree/rank ----------------
// Each gemm block: 128 rows x 64 cols (one col-half). W-half = 128x64 fp32 = 32 KB LDS,
// staged ONCE -> barrier-free K-loop (R4 property) at 5 blocks/CU (vs R4's 2).
// cg = wave id -> Wlds reads wave-uniform (broadcast, no bank conflicts).
__global__ __launch_bounds__(256) void gemm1_att1_degree_kernel(
    const float* __restrict__ X, const float* __restrict__ W,
    __hip_bfloat16* __restrict__ Y,
    const float* __restrict__ att_src, const float* __restrict__ att_dst,
    float* __restrict__ a_s, float* __restrict__ a_d,
    const int* __restrict__ dst, int* __restrict__ deg, int* __restrict__ rank) {
    __shared__ float Wlds[128 * 64];  // 32 KB
    if (blockIdx.x >= GB1) {
        int t0 = (blockIdx.x - GB1) * 256 + threadIdx.x;
        const int stride = DEGB * 256;
#pragma unroll
        for (int u = 0; u < 4; ++u) {
            int i = t0 + u * stride;
            if (i < N_EDGES) rank[i] = atomicAdd(&deg[dst[i]], 1);
        }
        return;
    }
    int tid = threadIdx.x;
    int rb = blockIdx.x >> 1;
    int half = blockIdx.x & 1;     // col-half: cols [half*64, half*64+64)
    int cg = tid >> 6;             // wave id 0..3 -> 16 cols each
    int rg = tid & 63;
    int c0 = cg * 16;              // within half
    int gc0 = half * 64 + c0;      // global col
    int r0 = rb * 128 + rg * 2;

    // stage W-half: rows k=0..127, cols [half*64 .. +64)
    for (int idx = tid; idx < 128 * 16; idx += 256) {
        int k = idx >> 4;
        int c4 = idx & 15;
        *(float4*)&Wlds[k * 64 + c4 * 4] =
            *(const float4*)&W[(size_t)k * 128 + half * 64 + c4 * 4];
    }
    __syncthreads();

    float acc[2][16];
#pragma unroll
    for (int i = 0; i < 2; ++i)
#pragma unroll
        for (int j = 0; j < 16; ++j) acc[i][j] = 0.f;

    const float* xrow[2];
#pragma unroll
    for (int i = 0; i < 2; ++i) {
        int ri = r0 + i;
        if (ri >= N_NODES) ri = N_NODES - 1;
        xrow[i] = X + (size_t)ri * 128;
    }

    for (int k = 0; k < 128; k += 4) {
        float4 xv[2];
#pragma unroll
        for (int i = 0; i < 2; ++i) xv[i] = *(const float4*)&xrow[i][k];
#pragma unroll
        for (int kk = 0; kk < 4; ++kk) {
            const float* wrow = &Wlds[(k + kk) * 64 + c0];
            const float4 w0 = *(const float4*)(wrow + 0);
            const float4 w1 = *(const float4*)(wrow + 4);
            const float4 w2 = *(const float4*)(wrow + 8);
            const float4 w3 = *(const float4*)(wrow + 12);
#pragma unroll
            for (int i = 0; i < 2; ++i) {
                float xk = (kk == 0) ? xv[i].x : (kk == 1) ? xv[i].y : (kk == 2) ? xv[i].z : xv[i].w;
                acc[i][0]  += xk * w0.x; acc[i][1]  += xk * w0.y;
                acc[i][2]  += xk * w0.z; acc[i][3]  += xk * w0.w;
                acc[i][4]  += xk * w1.x; acc[i][5]  += xk * w1.y;
                acc[i][6]  += xk * w1.z; acc[i][7]  += xk * w1.w;
                acc[i][8]  += xk * w2.x; acc[i][9]  += xk * w2.y;
                acc[i][10] += xk * w2.z; acc[i][11] += xk * w2.w;
                acc[i][12] += xk * w3.x; acc[i][13] += xk * w3.y;
                acc[i][14] += xk * w3.z; acc[i][15] += xk * w3.w;
            }
        }
    }

    // h1pre bf16 store (per lane: 2 rows x 16 cols = 32B contiguous each)
#pragma unroll
    for (int i = 0; i < 2; ++i) {
        int r = r0 + i;
        if (r < N_NODES) {
            __hip_bfloat162* yp = (__hip_bfloat162*)(Y + (size_t)r * 128 + gc0);
#pragma unroll
            for (int j = 0; j < 8; ++j) {
                __hip_bfloat162 p;
                p.x = __float2bfloat16(acc[i][2 * j]);
                p.y = __float2bfloat16(acc[i][2 * j + 1]);
                yp[j] = p;
            }
        }
    }

    // att1: partial dot per wave (16 cols), cross-wave reduce via Wlds scratch.
    // head for this wave = half*2 + (cg>>1); its 32 cols split across wave pair (cg even/odd).
    int head = half * 2 + (cg >> 1);
    float asv[16], adv[16];
#pragma unroll
    for (int j = 0; j < 16; ++j) {
        asv[j] = att_src[head * 32 + (cg & 1) * 16 + j];
        adv[j] = att_dst[head * 32 + (cg & 1) * 16 + j];
    }
    float ps[2], pd[2];
#pragma unroll
    for (int i = 0; i < 2; ++i) {
        ps[i] = 0.f; pd[i] = 0.f;
#pragma unroll
        for (int j = 0; j < 16; ++j) {
            ps[i] += acc[i][j] * asv[j];
            pd[i] += acc[i][j] * adv[j];
        }
    }
    __syncthreads();  // all waves done reading Wlds -> reuse as scratch
    float* red = Wlds;
#pragma unroll
    for (int i = 0; i < 2; ++i) {
        int rr = rg * 2 + i;  // 0..127
        red[rr * 4 + cg] = ps[i];
        red[512 + rr * 4 + cg] = pd[i];
    }
    __syncthreads();
    if (tid < 128) {
        int r = rb * 128 + tid;
        if (r < N_NODES) {
            // waves {0,1} -> head half*2 ; waves {2,3} -> head half*2+1
            float as0 = red[tid * 4 + 0] + red[tid * 4 + 1];
            float as1 = red[tid * 4 + 2] + red[tid * 4 + 3];
            float ad0 = red[512 + tid * 4 + 0] + red[512 + tid * 4 + 1];
            float ad1 = red[512 + tid * 4 + 2] + red[512 + tid * 4 + 3];
            a_s[r * 4 + half * 2 + 0] = as0;
            a_s[r * 4 + half * 2 + 1] = as1;
            a_d[r * 4 + half * 2 + 0] = ad0;
            a_d[r * 4 + half * 2 + 1] = ad1;
        }
    }
}

// ---------------- scans ----------------
__global__ __launch_bounds__(256) void scan1_kernel(const int* __restrict__ deg,
                                                    int* __restrict__ rpl,
                                                    int* __restrict__ bsum) {
    int i = blockIdx.x * 256 + threadIdx.x;
    int v = (i < N_NODES) ? deg[i] : 0;
    int lane = threadIdx.x & 63;
    int w = threadIdx.x >> 6;
    int x = v;
#pragma unroll
    for (int off = 1; off < 64; off <<= 1) {
        int t = __shfl_up(x, off, 64);
        if (lane >= off) x += t;
    }
    __shared__ int wsum[4];
    if (lane == 63) wsum[w] = x;
    __syncthreads();
    int wo = 0;
    if (w > 0) wo += wsum[0];
    if (w > 1) wo += wsum[1];
    if (w > 2) wo += wsum[2];
    if (i <= N_NODES) rpl[i] = x - v + wo;
    if (threadIdx.x == 255) bsum[blockIdx.x] = x + wo;
}

__global__ __launch_bounds__(256) void scan2_kernel(const int* __restrict__ bsum,
                                                    int* __restrict__ boff) {
    int i = threadIdx.x;
    int v = (i < NB_SCAN) ? bsum[i] : 0;
    int lane = threadIdx.x & 63;
    int w = threadIdx.x >> 6;
    int x = v;
#pragma unroll
    for (int off = 1; off < 64; off <<= 1) {
        int t = __shfl_up(x, off, 64);
        if (lane >= off) x += t;
    }
    __shared__ int wsum[4];
    if (lane == 63) wsum[w] = x;
    __syncthreads();
    int wo = 0;
    if (w > 0) wo += wsum[0];
    if (w > 1) wo += wsum[1];
    if (w > 2) wo += wsum[2];
    if (i < NB_SCAN) boff[i] = x - v + wo;
}

// ---------------- scatter (no atomics: rank precomputed) ----------------
__global__ __launch_bounds__(256) void scatter_kernel(const int* __restrict__ src,
                                                      const int* __restrict__ dst,
                                                      const int* __restrict__ rpl,
                                                      const int* __restrict__ boff,
                                                      const int* __restrict__ rank,
                                                      int* __restrict__ col) {
    int i = blockIdx.x * blockDim.x + threadIdx.x;
    if (i < N_EDGES) {
        int d = dst[i];
        int pos = rpl[d] + boff[d >> 8] + rank[i];
        col[pos] = src[i];
    }
}

// ---------------- aggregation layer 1 ----------------
__global__ __launch_bounds__(256) void agg1_kernel(const __hip_bfloat16* __restrict__ h,
                                                   const float* __restrict__ a_s,
                                                   const float* __restrict__ a_d,
                                                   const int* __restrict__ rpl,
                                                   const int* __restrict__ boff,
                                                   const int* __restrict__ col,
                                                   const float* __restrict__ b1,
                                                   const float* __restrict__ gamma,
                                                   const float* __restrict__ beta,
                                                   float* __restrict__ out) {
    __shared__ int colsh[4][CAP];
    __shared__ float wsh[4][CAP * 4];
    int wv = threadIdx.x >> 6;
    int lane = threadIdx.x & 63;
    int n = blockIdx.x * 4 + wv;
    int nn = (n < N_NODES) ? n : N_NODES - 1;
    int head = lane >> 4;
    int c = 2 * lane;

    const float4 ad4 = *(const float4*)&a_d[nn * 4];
    int beg = rpl[nn] + boff[nn >> 8];
    int end = rpl[nn + 1] + boff[(nn + 1) >> 8];
    int deg = end - beg;

    float den0 = 0.f, den1 = 0.f, den2 = 0.f, den3 = 0.f;
    for (int t = lane; t < deg; t += 64) {
        int s = col[beg + t];
        const float4 as4 = *(const float4*)&a_s[s * 4];
        float w0 = __expf(lrelu(as4.x + ad4.x));
        float w1 = __expf(lrelu(as4.y + ad4.y));
        float w2 = __expf(lrelu(as4.z + ad4.z));
        float w3 = __expf(lrelu(as4.w + ad4.w));
        if (t < CAP) {
            colsh[wv][t] = s;
            *(float4*)&wsh[wv][t * 4] = make_float4(w0, w1, w2, w3);
        }
        den0 += w0; den1 += w1; den2 += w2; den3 += w3;
    }
#pragma unroll
    for (int m = 1; m < 64; m <<= 1) {
        den0 += __shfl_xor(den0, m, 64);
        den1 += __shfl_xor(den1, m, 64);
        den2 += __shfl_xor(den2, m, 64);
        den3 += __shfl_xor(den3, m, 64);
    }
    float adh = (head == 0) ? ad4.x : (head == 1) ? ad4.y : (head == 2) ? ad4.z : ad4.w;
    float wself = __expf(lrelu(a_s[nn * 4 + head] + adh));
    float den = ((head == 0) ? den0 : (head == 1) ? den1 : (head == 2) ? den2 : den3) + wself;

    __syncthreads();

    float ax0 = 0.f, ay0 = 0.f, ax1 = 0.f, ay1 = 0.f;
    int m0 = (deg < CAP) ? deg : CAP;
    int j = 0;
    for (; j + 3 < m0; j += 4) {
        int s0 = colsh[wv][j + 0], s1 = colsh[wv][j + 1];
        int s2 = colsh[wv][j + 2], s3 = colsh[wv][j + 3];
        float w0 = wsh[wv][(j + 0) * 4 + head], w1 = wsh[wv][(j + 1) * 4 + head];
        float w2 = wsh[wv][(j + 2) * 4 + head], w3 = wsh[wv][(j + 3) * 4 + head];
        __hip_bfloat162 h0 = ((const __hip_bfloat162*)h)[(size_t)s0 * 64 + lane];
        __hip_bfloat162 h1 = ((const __hip_bfloat162*)h)[(size_t)s1 * 64 + lane];
        __hip_bfloat162 h2v = ((const __hip_bfloat162*)h)[(size_t)s2 * 64 + lane];
        __hip_bfloat162 h3 = ((const __hip_bfloat162*)h)[(size_t)s3 * 64 + lane];
        ax0 += w0 * bf2f(h0.x); ay0 += w0 * bf2f(h0.y);
        ax1 += w1 * bf2f(h1.x); ay1 += w1 * bf2f(h1.y);
        ax0 += w2 * bf2f(h2v.x); ay0 += w2 * bf2f(h2v.y);
        ax1 += w3 * bf2f(h3.x); ay1 += w3 * bf2f(h3.y);
    }
    for (; j < m0; ++j) {
        int s = colsh[wv][j];
        float w = wsh[wv][j * 4 + head];
        __hip_bfloat162 hv = ((const __hip_bfloat162*)h)[(size_t)s * 64 + lane];
        ax0 += w * bf2f(hv.x); ay0 += w * bf2f(hv.y);
    }
    for (; j < deg; ++j) {
        int s = col[beg + j];
        float w = __expf(lrelu(a_s[s * 4 + head] + adh));
        __hip_bfloat162 hv = ((const __hip_bfloat162*)h)[(size_t)s * 64 + lane];
        ax0 += w * bf2f(hv.x); ay0 += w * bf2f(hv.y);
    }
    {
        __hip_bfloat162 hv = ((const __hip_bfloat162*)h)[(size_t)nn * 64 + lane];
        ax0 += wself * bf2f(hv.x); ay0 += wself * bf2f(hv.y);
    }
    float inv = 1.f / den;
    float vx = (ax0 + ax1) * inv + b1[c];
    float vy = (ay0 + ay1) * inv + b1[c + 1];

    float s1 = vx + vy, s2 = vx * vx + vy * vy;
#pragma unroll
    for (int m = 1; m < 64; m <<= 1) {
        s1 += __shfl_xor(s1, m, 64);
        s2 += __shfl_xor(s2, m, 64);
    }
    float mean = s1 * (1.f / 128.f);
    float var = s2 * (1.f / 128.f) - mean * mean;
    float r = rsqrtf(var + LN_EPS);
    float ox = fmaxf(0.f, (vx - mean) * r * gamma[c] + beta[c]);
    float oy = fmaxf(0.f, (vy - mean) * r * gamma[c + 1] + beta[c + 1]);
    if (n < N_NODES) *(float2*)&out[(size_t)n * 128 + c] = make_float2(ox, oy);
}

// ---------------- gemm2 + att2 epilogue ----------------
// Whole W2 (128x64 fp32 = 32 KB) staged once -> barrier-free K-loop.
// cg = wave id -> broadcast W reads. Wlds reused for att2 cross-wave reduce.
__global__ __launch_bounds__(256) void gemm2_att2_kernel(const float* __restrict__ X,
                                                         const float* __restrict__ W,
                                                         __hip_bfloat16* __restrict__ Y,
                                                         const float* __restrict__ att_src,
                                                         const float* __restrict__ att_dst,
                                                         float* __restrict__ a_s,
                                                         float* __restrict__ a_d) {
    __shared__ float Wlds[128 * 64];  // 32 KB
    int tid = threadIdx.x;
    int cg = tid >> 6;
    int rg = tid & 63;
    int c0 = cg * 16;
    int r0 = blockIdx.x * 128 + rg * 2;

    for (int idx = tid; idx < 128 * 16; idx += 256) {
        ((float4*)Wlds)[idx] = ((const float4*)W)[idx];
    }
    __syncthreads();

    float acc[2][16];
#pragma unroll
    for (int i = 0; i < 2; ++i)
#pragma unroll
        for (int j = 0; j < 16; ++j) acc[i][j] = 0.f;

    const float* xrow[2];
#pragma unroll
    for (int i = 0; i < 2; ++i) {
        int ri = r0 + i;
        if (ri >= N_NODES) ri = N_NODES - 1;
        xrow[i] = X + (size_t)ri * 128;
    }

    for (int k = 0; k < 128; k += 4) {
        float4 xv[2];
#pragma unroll
        for (int i = 0; i < 2; ++i) xv[i] = *(const float4*)&xrow[i][k];
#pragma unroll
        for (int kk = 0; kk < 4; ++kk) {
            const float* wrow = &Wlds[(k + kk) * 64 + c0];
            const float4 w0 = *(const float4*)(wrow + 0);
            const float4 w1 = *(const float4*)(wrow + 4);
            const float4 w2 = *(const float4*)(wrow + 8);
            const float4 w3 = *(const float4*)(wrow + 12);
#pragma unroll
            for (int i = 0; i < 2; ++i) {
                float xk = (kk == 0) ? xv[i].x : (kk == 1) ? xv[i].y : (kk == 2) ? xv[i].z : xv[i].w;
                acc[i][0]  += xk * w0.x; acc[i][1]  += xk * w0.y;
                acc[i][2]  += xk * w0.z; acc[i][3]  += xk * w0.w;
                acc[i][4]  += xk * w1.x; acc[i][5]  += xk * w1.y;
                acc[i][6]  += xk * w1.z; acc[i][7]  += xk * w1.w;
                acc[i][8]  += xk * w2.x; acc[i][9]  += xk * w2.y;
                acc[i][10] += xk * w2.z; acc[i][11] += xk * w2.w;
                acc[i][12] += xk * w3.x; acc[i][13] += xk * w3.y;
                acc[i][14] += xk * w3.z; acc[i][15] += xk * w3.w;
            }
        }
    }

#pragma unroll
    for (int i = 0; i < 2; ++i) {
        int r = r0 + i;
        if (r < N_NODES) {
            __hip_bfloat162* yp = (__hip_bfloat162*)(Y + (size_t)r * 64 + c0);
#pragma unroll
            for (int j = 0; j < 8; ++j) {
                __hip_bfloat162 p;
                p.x = __float2bfloat16(acc[i][2 * j]);
                p.y = __float2bfloat16(acc[i][2 * j + 1]);
                yp[j] = p;
            }
        }
    }

    float ps[2], pd[2];
#pragma unroll
    for (int i = 0; i < 2; ++i) {
        ps[i] = 0.f; pd[i] = 0.f;
#pragma unroll
        for (int j = 0; j < 16; ++j) {
            ps[i] += acc[i][j] * att_src[c0 + j];
            pd[i] += acc[i][j] * att_dst[c0 + j];
        }
    }
    __syncthreads();  // done with W in Wlds
    float* red = Wlds;
#pragma unroll
    for (int i = 0; i < 2; ++i) {
        int rr = rg * 2 + i;
        red[rr * 4 + cg] = ps[i];
        red[512 + rr * 4 + cg] = pd[i];
    }
    __syncthreads();
    if (tid < 128) {
        int r = blockIdx.x * 128 + tid;
        float as = red[tid * 4 + 0] + red[tid * 4 + 1] + red[tid * 4 + 2] + red[tid * 4 + 3];
        float ad = red[512 + tid * 4 + 0] + red[512 + tid * 4 + 1] +
                   red[512 + tid * 4 + 2] + red[512 + tid * 4 + 3];
        if (r < N_NODES) {
            a_s[r] = as;
            a_d[r] = ad;
        }
    }
}

// ---------------- aggregation layer 2 ----------------
__global__ __launch_bounds__(256) void agg2_kernel(const __hip_bfloat16* __restrict__ h,
                                                   const float* __restrict__ a_s,
                                                   const float* __restrict__ a_d,
                                                   const int* __restrict__ rpl,
                                                   const int* __restrict__ boff,
                                                   const int* __restrict__ col,
                                                   const float* __restrict__ b2,
                                                   const float* __restrict__ gamma,
                                                   const float* __restrict__ beta,
                                                   float* __restrict__ out) {
    __shared__ int colsh[4][CAP];
    __shared__ float wsh[4][CAP];
    int wv = threadIdx.x >> 6;
    int lane = threadIdx.x & 63;
    int n = blockIdx.x * 4 + wv;
    int nn = (n < N_NODES) ? n : N_NODES - 1;

    float adh = a_d[nn];
    int beg = rpl[nn] + boff[nn >> 8];
    int end = rpl[nn + 1] + boff[(nn + 1) >> 8];
    int deg = end - beg;

    float den = 0.f;
    for (int t = lane; t < deg; t += 64) {
        int s = col[beg + t];
        float w = __expf(lrelu(a_s[s] + adh));
        if (t < CAP) {
            colsh[wv][t] = s;
            wsh[wv][t] = w;
        }
        den += w;
    }
#pragma unroll
    for (int m = 1; m < 64; m <<= 1) den += __shfl_xor(den, m, 64);
    float wself = __expf(lrelu(a_s[nn] + adh));
    den += wself;

    __syncthreads();

    float a0 = 0.f, a1 = 0.f;
    int m0 = (deg < CAP) ? deg : CAP;
    int j = 0;
    for (; j + 3 < m0; j += 4) {
        int s0 = colsh[wv][j + 0], s1 = colsh[wv][j + 1];
        int s2 = colsh[wv][j + 2], s3 = colsh[wv][j + 3];
        float w0 = wsh[wv][j + 0], w1 = wsh[wv][j + 1];
        float w2 = wsh[wv][j + 2], w3 = wsh[wv][j + 3];
        a0 += w0 * bf2f(h[(size_t)s0 * 64 + lane]);
        a1 += w1 * bf2f(h[(size_t)s1 * 64 + lane]);
        a0 += w2 * bf2f(h[(size_t)s2 * 64 + lane]);
        a1 += w3 * bf2f(h[(size_t)s3 * 64 + lane]);
    }
    for (; j < m0; ++j) {
        a0 += wsh[wv][j] * bf2f(h[(size_t)colsh[wv][j] * 64 + lane]);
    }
    for (; j < deg; ++j) {
        int s = col[beg + j];
        float w = __expf(lrelu(a_s[s] + adh));
        a0 += w * bf2f(h[(size_t)s * 64 + lane]);
    }
    a0 += wself * bf2f(h[(size_t)nn * 64 + lane]);

    float v = (a0 + a1) / den + b2[lane];

    float s1 = v, s2 = v * v;
#pragma unroll
    for (int m = 1; m < 64; m <<= 1) {
        s1 += __shfl_xor(s1, m, 64);
        s2 += __shfl_xor(s2, m, 64);
    }
    float mean = s1 * (1.f / 64.f);
    float var = s2 * (1.f / 64.f) - mean * mean;
    float r = rsqrtf(var + LN_EPS);
    if (n < N_NODES) out[(size_t)n * 64 + lane] = (v - mean) * r * gamma[lane] + beta[lane];
}

// ---------------- host ----------------
extern "C" void kernel_launch(void* const* d_in, const int* in_sizes, int n_in,
                              void* d_out, int out_size, void* d_ws, size_t ws_size,
                              hipStream_t stream) {
    const float* x        = (const float*)d_in[0];
    const int*   ei       = (const int*)d_in[1];
    const float* W1       = (const float*)d_in[2];
    const float* att_src1 = (const float*)d_in[3];
    const float* att_dst1 = (const float*)d_in[4];
    const float* b1       = (const float*)d_in[5];
    const float* gamma1   = (const float*)d_in[6];
    const float* beta1    = (const float*)d_in[7];
    const float* W2       = (const float*)d_in[8];
    const float* att_src2 = (const float*)d_in[9];
    const float* att_dst2 = (const float*)d_in[10];
    const float* b2       = (const float*)d_in[11];
    const float* gamma2   = (const float*)d_in[12];
    const float* beta2    = (const float*)d_in[13];
    const int* src = ei;
    const int* dst = ei + N_EDGES;
    float* out = (float*)d_out;

    char* ws = (char*)d_ws;
    size_t off = 0;
    auto alloc = [&](size_t bytes) -> void* {
        void* p = ws + off;
        off += bytes;
        off = (off + 255) & ~(size_t)255;
        return p;
    };
    __hip_bfloat16* h1pre = (__hip_bfloat16*)alloc((size_t)N_NODES * 128 * 2);
    __hip_bfloat16* h2pre = (__hip_bfloat16*)alloc((size_t)N_NODES * 64 * 2);
    float* a_s1   = (float*)alloc((size_t)N_NODES * 4 * 4);
    float* a_d1   = (float*)alloc((size_t)N_NODES * 4 * 4);
    float* h1n    = (float*)alloc((size_t)N_NODES * 128 * 4);
    float* a_s2   = (float*)alloc((size_t)N_NODES * 4);
    float* a_d2   = (float*)alloc((size_t)N_NODES * 4);
    int* deg      = (int*)alloc((size_t)N_NODES * 4);
    int* rpl      = (int*)alloc((size_t)(N_NODES + 1) * 4);
    int* col      = (int*)alloc((size_t)N_EDGES * 4);
    int* rank     = (int*)alloc((size_t)N_EDGES * 4);
    int* bsum     = (int*)alloc((size_t)NB_SCAN * 4);
    int* boff     = (int*)alloc((size_t)NB_SCAN * 4);

    hipMemsetAsync(deg, 0, (size_t)N_NODES * 4, stream);

    const int EB = (N_EDGES + 255) / 256;
    const int NWB = (N_NODES + 3) / 4;

    gemm1_att1_degree_kernel<<<GB1 + DEGB, 256, 0, stream>>>(
        x, W1, h1pre, att_src1, att_dst1, a_s1, a_d1, dst, deg, rank);
    scan1_kernel<<<NB_SCAN, 256, 0, stream>>>(deg, rpl, bsum);
    scan2_kernel<<<1, 256, 0, stream>>>(bsum, boff);
    scatter_kernel<<<EB, 256, 0, stream>>>(src, dst, rpl, boff, rank, col);

    agg1_kernel<<<NWB, 256, 0, stream>>>(h1pre, a_s1, a_d1, rpl, boff, col, b1, gamma1, beta1, h1n);

    gemm2_att2_kernel<<<(N_NODES + 127) / 128, 256, 0, stream>>>(
        h1n, W2, h2pre, att_src2, att_dst2, a_s2, a_d2);
    agg2_kernel<<<NWB, 256, 0, stream>>>(h2pre, a_s2, a_d2, rpl, boff, col, b2, gamma2, beta2, out);
}